// Round 8
// baseline (665.258 us; speedup 1.0000x reference)
//
#include <hip/hip_runtime.h>

typedef __bf16 bf16;
typedef __attribute__((ext_vector_type(4))) float f32x4;
typedef __attribute__((ext_vector_type(8))) __bf16 bf16x8;
typedef __attribute__((ext_vector_type(4))) __bf16 bf16x4;
typedef __attribute__((ext_vector_type(4))) int i32x4;

#define NN 8192
#define FI 512
#define FO 256

#define MFMA16 __builtin_amdgcn_mfma_f32_16x16x32_bf16

// Direct global->LDS async copy, 16B per lane. LDS dst is wave-uniform base;
// HW writes lane i at base + i*16. Global src is per-lane (so the SOURCE can
// be permuted to realize any LDS layout -- rule #21). No VGPR dest => the
// compiler cannot serialize these on register reuse (the R2/R4/R6 trap).
__device__ static inline void gld16(const bf16* g, bf16* l) {
  __builtin_amdgcn_global_load_lds(
      (const __attribute__((address_space(1))) unsigned int*)(g),
      (__attribute__((address_space(3))) unsigned int*)(l), 16, 0, 0);
}

// ---------------------------------------------------------------------------
// kw: W [512][256] f32 -> Wt_hi/Wt_lo [256][512] bf16 (transposed + split),
// so k1 can load B fragments straight from global (bf16x8 per lane).
// ---------------------------------------------------------------------------
__global__ __launch_bounds__(256) void kw_split(const float* __restrict__ W,
                                                bf16* __restrict__ wth,
                                                bf16* __restrict__ wtl) {
  const int idx = blockIdx.x * 256 + threadIdx.x;  // 512*256 = 131072
  const int k = idx >> 8, n = idx & 255;
  float x = W[idx];
  bf16 hi = (bf16)x;
  wth[(size_t)n * FI + k] = hi;
  wtl[(size_t)n * FI + k] = (bf16)(x - (float)hi);
}

// ---------------------------------------------------------------------------
// k1: Wh = h @ W + bW via split-bf16 MFMA (hi*hi + hi*lo + lo*hi, fp32 acc).
// Barrier-free main loop; wave = 16 rows x 64 cols (acc[4]). Short K (16
// steps) and L2-resident wth/wtl keep the (known) serialized-B-load cost
// modest. Epilogue stages whb through LDS -> one coalesced 8 KB linear store
// per block; f1/f2 via shfl-reduce + atomicAdd. Grid (256,2) = 512 blocks.
// ---------------------------------------------------------------------------
__global__ __launch_bounds__(256, 2) void k1_gemm(
    const float* __restrict__ h, const bf16* __restrict__ wth,
    const bf16* __restrict__ wtl, const float* __restrict__ bW,
    const float* __restrict__ a1, const float* __restrict__ a2,
    bf16* __restrict__ whb, float* __restrict__ f1, float* __restrict__ f2) {
  __shared__ bf16 stg[128 * 32];  // [n_local][il], 8 KB
  const int t = threadIdx.x;
  const int lane = t & 63, w = t >> 6;
  const int m16 = lane & 15, q = lane >> 4;
  const int wr = w & 1, wn = w >> 1;
  const int rb = blockIdx.x, bj = blockIdx.y;
  const int row = rb * 32 + wr * 16 + m16;  // A-fragment row for this lane
  const int nb = bj * 128 + wn * 64;

  const f32x4 z4 = {0.f, 0.f, 0.f, 0.f};
  f32x4 acc[4];
#pragma unroll
  for (int nn = 0; nn < 4; ++nn) acc[nn] = z4;

  const float* hrow = h + (size_t)row * FI + q * 8;
  const bf16* wthp = wth + (size_t)(nb + m16) * FI + q * 8;
  const bf16* wtlp = wtl + (size_t)(nb + m16) * FI + q * 8;

  f32x4 nh0 = *(const f32x4*)(hrow);
  f32x4 nh1 = *(const f32x4*)(hrow + 4);

  const int KT = FI / 32;
  for (int kt = 0; kt < KT; ++kt) {
    bf16x8 bh[4], bl[4];
#pragma unroll
    for (int nn = 0; nn < 4; ++nn) {
      const size_t woff = (size_t)(nn * 16) * FI + kt * 32;
      bh[nn] = *(const bf16x8*)(wthp + woff);
      bl[nn] = *(const bf16x8*)(wtlp + woff);
    }
    const f32x4 h0 = nh0, h1 = nh1;
    const int ktn = (kt + 1 < KT) ? kt + 1 : kt;
    nh0 = *(const f32x4*)(hrow + ktn * 32);
    nh1 = *(const f32x4*)(hrow + ktn * 32 + 4);
    bf16x8 hh, hl;
#pragma unroll
    for (int x = 0; x < 4; ++x) {
      float v = h0[x];
      bf16 hi = (bf16)v;
      hh[x] = hi;
      hl[x] = (bf16)(v - (float)hi);
      float v2 = h1[x];
      bf16 hi2 = (bf16)v2;
      hh[4 + x] = hi2;
      hl[4 + x] = (bf16)(v2 - (float)hi2);
    }
#pragma unroll
    for (int nn = 0; nn < 4; ++nn) {
      acc[nn] = MFMA16(hh, bh[nn], acc[nn], 0, 0, 0);
      acc[nn] = MFMA16(hl, bh[nn], acc[nn], 0, 0, 0);
      acc[nn] = MFMA16(hh, bl[nn], acc[nn], 0, 0, 0);
    }
  }
  // Epilogue. C/D layout: col = lane&15 (n), row = q*4+reg (i within 16-tile).
  float f1p[4] = {}, f2p[4] = {};
  const int il = wr * 16 + q * 4;
#pragma unroll
  for (int nn = 0; nn < 4; ++nn) {
    const int n = nb + nn * 16 + m16;
    const int nl = wn * 64 + nn * 16 + m16;  // local n within block (0..127)
    const float bw = bW[n], av1 = a1[n], av2 = a2[n];
    bf16x4 st;
#pragma unroll
    for (int reg = 0; reg < 4; ++reg) {
      float wh = acc[nn][reg] + bw;
      st[reg] = (bf16)wh;
      f1p[reg] += wh * av1;
      f2p[reg] += wh * av2;
    }
    *(bf16x4*)&stg[nl * 32 + il] = st;
  }
#pragma unroll
  for (int m = 1; m < 16; m <<= 1) {
#pragma unroll
    for (int reg = 0; reg < 4; ++reg) {
      f1p[reg] += __shfl_xor(f1p[reg], m);
      f2p[reg] += __shfl_xor(f2p[reg], m);
    }
  }
  if (m16 == 0) {
#pragma unroll
    for (int reg = 0; reg < 4; ++reg) {
      const int i = rb * 32 + wr * 16 + q * 4 + reg;
      atomicAdd(&f1[i], f1p[reg]);
      atomicAdd(&f2[i], f2p[reg]);
    }
  }
  __syncthreads();
  // Coalesced whb store: block region is 4096 contiguous bf16 (8 KB).
  bf16x8* dst = (bf16x8*)(whb + (size_t)rb * (FO * 32) + (size_t)bj * (128 * 32));
  const bf16x8* srcv = (const bf16x8*)stg;
#pragma unroll
  for (int u = 0; u < 2; ++u) dst[t * 2 + u] = srcv[t * 2 + u];
}

// ---------------------------------------------------------------------------
// k4a: masked exp-scores, pure streaming (no LDS, no barriers, no MFMA).
// Wave = 16 rows x 512 j; lane (m16,q) scores row m16, j = q*8..+7 per 32-j
// tile = exactly one MFMA A-fragment lane -> P tile written as 64 lanes x
// bf16x8 = 1 KB coalesced. One atomicAdd per row per wave into l (prezeroed).
// Softmax shift: sh = lrelu(ci + 8) >= row max (|f2| << 8); cancels exactly
// in num/denom. 8192 waves = 2048 blocks; adj 268 MB R + P 134 MB W.
// ---------------------------------------------------------------------------
__global__ __launch_bounds__(256) void k4a_scores(
    const int* __restrict__ adj, const float* __restrict__ f1,
    const float* __restrict__ f2, const float* __restrict__ ba_p,
    bf16* __restrict__ P, float* __restrict__ l) {
  const int t = threadIdx.x;
  const int lane = t & 63, w = t >> 6;
  const int m16 = lane & 15, q = lane >> 4;
  const int gw = blockIdx.x * 4 + w;  // 0..8191
  const int ib = gw >> 4;             // row-tile (16 rows), 0..511
  const int js = gw & 15;             // j-split (512 j), 0..15
  const int row = ib * 16 + m16;
  const int j0 = js * 512;

  const float ba = *ba_p;
  const float ci = f1[row] + ba;
  const float arg0 = ci + 8.0f;
  const float sh = fmaxf(arg0, 0.2f * arg0);

  const int* arow = adj + (size_t)row * NN + j0 + q * 8;
  const float* frow = f2 + j0 + q * 8;
  // P tile a = ib*256 + js*16 + jt; lane slot = tile*512 + lane*8
  bf16* ptile = P + (size_t)(ib * 256 + js * 16) * 512 + lane * 8;

  float lreg = 0.f;
#pragma unroll 4
  for (int jt = 0; jt < 16; ++jt) {
    i32x4 a0 = *(const i32x4*)(arow + jt * 32);
    i32x4 a1 = *(const i32x4*)(arow + jt * 32 + 4);
    f32x4 g0 = *(const f32x4*)(frow + jt * 32);
    f32x4 g1 = *(const f32x4*)(frow + jt * 32 + 4);
    float pv[8];
#pragma unroll
    for (int x = 0; x < 4; ++x) {
      float arg = ci + g0[x];
      float e = fmaxf(arg, 0.2f * arg);
      pv[x] = (a0[x] > 0) ? __expf(e - sh) : 0.f;
      float arg2 = ci + g1[x];
      float e2 = fmaxf(arg2, 0.2f * arg2);
      pv[4 + x] = (a1[x] > 0) ? __expf(e2 - sh) : 0.f;
    }
    bf16x8 pb;
#pragma unroll
    for (int x = 0; x < 8; ++x) {
      lreg += pv[x];
      pb[x] = (bf16)pv[x];
    }
    *(bf16x8*)(ptile + (size_t)jt * 512) = pb;
  }
  // sum over the 4 q-lanes sharing a row, then one atomic per row
  lreg += __shfl_xor(lreg, 16);
  lreg += __shfl_xor(lreg, 32);
  if (q == 0) atomicAdd(&l[row], lreg);
}

// ---------------------------------------------------------------------------
// k4b: out = (P @ Wh) / l.  M=8192, N=256 (full, P read ONCE), K=8192.
// 3-buffer global_load_lds pipeline with COUNTED vmcnt (T4): stage kt+2 each
// iteration; s_waitcnt vmcnt(2L) where L = this wave's loads/step -- buf kt
// was issued two iterations ago so the wait is free in steady state. Raw
// s_barrier (never vmcnt(0) in the loop; R7's __syncthreads drain was the
// 700cyc/step cost). Bank conflicts (R7: 8.4M) eliminated by PRE-PERMUTED
// staging sources (rule #21): each 1KB fragment tile is staged with lane i
// loading the (m16=i&15,q=i>>4) granule, so LDS holds tiles in lane-read
// order and every ds_read_b128 is lane-linear.
// Block = 32 rows x 256 cols, 512 threads (8 waves: wr = m-tile, wn = n-
// quarter); K-step 32. Per step/block: 18 x 1KB chunks (A 2, B 16); per
// wave: waves 0,1 stage 3 chunks (A+2B, vmcnt literal 6), waves 2-7 stage
// 2 (vmcnt literal 4); then 5 ds_read_b128 + 4 MFMA. LDS 54 KB. Grid 256.
// ---------------------------------------------------------------------------
__global__ __launch_bounds__(512, 2) void k4b_gemm(
    const bf16* __restrict__ P, const bf16* __restrict__ whb,
    const float* __restrict__ l, float* __restrict__ out) {
  __shared__ bf16 Ab[3][2 * 512];    // [buf][m-tile][lane-slot], 2 KB/buf
  __shared__ bf16 Bb[3][16 * 512];   // [buf][n-tile][lane-slot], 16 KB/buf
  const int t = threadIdx.x;
  const int lane = t & 63, w = t >> 6;  // 8 waves
  const int m16 = lane & 15, q = lane >> 4;
  const int wr = w & 1, wn = w >> 1;    // wr: m-tile, wn: n-quarter (64 cols)
  const int rb = blockIdx.x;
  const int i0 = rb * 32;

  // epilogue l values: load FIRST so they never interleave with staged loads
  // (they retire during the prologue; vmcnt counting stays exact).
  const int r0 = i0 + wr * 16 + q * 4;
  float lv0 = l[r0], lv1 = l[r0 + 1], lv2 = l[r0 + 2], lv3 = l[r0 + 3];
  __builtin_amdgcn_sched_barrier(0);

  // staging sources. A (P) is already stored in lane-read order -> linear.
  // B (whb): pre-permuted so tile lands in lane-read order: lane i loads the
  // (m16=i&15, q=i>>4) granule of its 16n x 32k tile.
  const bf16* asrc = P + ((size_t)(rb * 2 + w) * 256) * 512 + lane * 8;  // w<2
  const size_t boff0 = (size_t)(((2 * w + 0) * 16 + (lane & 15)) * 32 + (lane >> 4) * 8);
  const size_t boff1 = (size_t)(((2 * w + 1) * 16 + (lane & 15)) * 32 + (lane >> 4) * 8);

#define K4B_STAGE(buf, kt)                                                    \
  {                                                                           \
    if (w < 2) gld16(asrc + (size_t)(kt) * 512, &Ab[buf][w * 512]);           \
    gld16(whb + (size_t)(kt) * 8192 + boff0, &Bb[buf][(2 * w + 0) * 512]);    \
    gld16(whb + (size_t)(kt) * 8192 + boff1, &Bb[buf][(2 * w + 1) * 512]);    \
  }

  const f32x4 z4 = {0.f, 0.f, 0.f, 0.f};
  f32x4 acc0 = z4, acc1 = z4, acc2 = z4, acc3 = z4;

  K4B_STAGE(0, 0);
  K4B_STAGE(1, 1);

  const int KB = NN / 32;  // 256
  int cur = 0;
  for (int kt = 0; kt < KB; ++kt) {
    const int ktn = (kt + 2 < KB) ? kt + 2 : KB - 1;  // clamped (never read)
    int bnext = cur + 2; if (bnext >= 3) bnext -= 3;
    K4B_STAGE(bnext, ktn);
    // counted wait: retires exactly buf[cur]'s loads (issued 2 iters ago)
    if (w < 2) {
      asm volatile("s_waitcnt vmcnt(6)" ::: "memory");
    } else {
      asm volatile("s_waitcnt vmcnt(4)" ::: "memory");
    }
    __builtin_amdgcn_s_barrier();   // everyone's buf[cur] chunks landed
    __builtin_amdgcn_sched_barrier(0);
    bf16x8 af = *(const bf16x8*)&Ab[cur][wr * 512 + lane * 8];
    const bf16* bb = &Bb[cur][(wn * 4) * 512 + lane * 8];
    bf16x8 b0 = *(const bf16x8*)(bb);
    bf16x8 b1 = *(const bf16x8*)(bb + 512);
    bf16x8 b2 = *(const bf16x8*)(bb + 1024);
    bf16x8 b3 = *(const bf16x8*)(bb + 1536);
    acc0 = MFMA16(af, b0, acc0, 0, 0, 0);
    acc1 = MFMA16(af, b1, acc1, 0, 0, 0);
    acc2 = MFMA16(af, b2, acc2, 0, 0, 0);
    acc3 = MFMA16(af, b3, acc3, 0, 0, 0);
    __builtin_amdgcn_sched_barrier(0);
    __builtin_amdgcn_s_barrier();   // reads of buf[cur] done before restage
    __builtin_amdgcn_sched_barrier(0);
    cur = (cur == 2) ? 0 : cur + 1;
  }
#undef K4B_STAGE

  // Epilogue: divide by l and store. C/D: col = lane&15 (n), row = q*4+reg.
  float rl[4] = {1.0f / lv0, 1.0f / lv1, 1.0f / lv2, 1.0f / lv3};
  f32x4 accs[4] = {acc0, acc1, acc2, acc3};
#pragma unroll
  for (int nn = 0; nn < 4; ++nn) {
    const int n = wn * 64 + nn * 16 + m16;
#pragma unroll
    for (int reg = 0; reg < 4; ++reg) {
      out[(size_t)(r0 + reg) * FO + n] = accs[nn][reg] * rl[reg];
    }
  }
}

// ---------------------------------------------------------------------------
// Workspace layout:
//   [0, 4MB)          whb  (bf16 Wh, fragment-major)
//   4MB               f1   (32 KB)
//   +32KB             f2   (32 KB)
//   +64KB             l    (32 KB)   <- f1/f2/l contiguous, one 96 KB memset
//   4MB+96KB          wth (256 KB), wtl (256 KB)
//   8MB               P    (bf16 scores, A-fragment-major, 134.2 MB)
// total ~143 MB
// ---------------------------------------------------------------------------
extern "C" void kernel_launch(void* const* d_in, const int* in_sizes, int n_in,
                              void* d_out, int out_size, void* d_ws, size_t ws_size,
                              hipStream_t stream) {
  const float* h   = (const float*)d_in[0];
  const int*   adj = (const int*)d_in[1];
  const float* W   = (const float*)d_in[2];
  const float* bW  = (const float*)d_in[3];
  const float* a1  = (const float*)d_in[4];
  const float* a2  = (const float*)d_in[5];
  const float* ba  = (const float*)d_in[6];
  float* out = (float*)d_out;

  char* ws = (char*)d_ws;
  bf16* whb = (bf16*)ws;
  float* f1 = (float*)(ws + 4u * 1024 * 1024);
  float* f2 = (float*)(ws + 4u * 1024 * 1024 + 32 * 1024);
  float* l  = (float*)(ws + 4u * 1024 * 1024 + 64 * 1024);
  bf16* wth = (bf16*)(ws + 4u * 1024 * 1024 + 96 * 1024);
  bf16* wtl = wth + (size_t)FO * FI;
  bf16* P   = (bf16*)(ws + 8u * 1024 * 1024);

  hipMemsetAsync(f1, 0, 96 * 1024, stream);  // zero f1+f2+l (atomic targets)

  kw_split<<<FI * FO / 256, 256, 0, stream>>>(W, wth, wtl);
  k1_gemm<<<dim3(NN / 32, 2), 256, 0, stream>>>(h, wth, wtl, bW, a1, a2, whb, f1, f2);
  k4a_scores<<<NN / 4, 256, 0, stream>>>(adj, f1, f2, ba, P, l);  // 2048 blocks
  k4b_gemm<<<NN / 32, 512, 0, stream>>>(P, whb, l, out);
}